// Round 6
// baseline (294.397 us; speedup 1.0000x reference)
//
#include <hip/hip_runtime.h>
#include <hip/hip_bf16.h>
#include <math.h>

#define NUM_EMB 8192
#define EMB_DIM 256
#define NTOK    16384      // 16 * 32 * 32
#define HW      1024
#define QELEMS  4194304    // 16 * 256 * 1024
#define DECAY   0.99f
#define OMD     0.01f
#define COMMIT  0.25f
#define EPS_    1e-5f
#define MARGIN  0.6f
#define NSLICE  16         // codes per slice = 512

typedef _Float16 h8 __attribute__((ext_vector_type(8)));
typedef float    f4 __attribute__((ext_vector_type(4)));

#define GLD16(gptr, lptr) \
  __builtin_amdgcn_global_load_lds((const __attribute__((address_space(1))) void*)(gptr), \
                                   (__attribute__((address_space(3))) void*)(lptr), 16, 0, 0)

__device__ __forceinline__ int imin3(int a, int b, int c) {
    int d; asm("v_min3_i32 %0, %1, %2, %3" : "=v"(d) : "v"(a), "v"(b), "v"(c)); return d;
}
__device__ __forceinline__ int imed3(int a, int b, int c) {
    int d; asm("v_med3_i32 %0, %1, %2, %3" : "=v"(d) : "v"(a), "v"(b), "v"(c)); return d;
}

// ---------------- k_prep: x->Ap(-2x, f16)+xT(f32), emb->Bp(f16), esq, zero counts --
// Ap is pre-scaled by -2 (exact pow2 f16 scale) so k_dist's MFMA accumulates -2*dot
// directly on top of a C-init of (esq+4096). Ap feeds ONLY k_dist; xT stays exact.
// Bp layout is read-order-major for k_dist: [bS][wn][t=nt*8+kc][j][lane][8] so the
// inner-loop B address is base + t*2048 elems with j folded into the load imm.
__global__ __launch_bounds__(256)
void k_prep(const float* __restrict__ x, const float* __restrict__ emb,
            _Float16* __restrict__ Ap, _Float16* __restrict__ Bp,
            float* __restrict__ xT, float* __restrict__ esq,
            float* __restrict__ counts) {
    int bb = blockIdx.x;
    if (bb < 2048) {
        int g = bb * 256 + threadIdx.x;
        int lane = g & 63;
        int kc = (g >> 6) & 7;
        int mt = g >> 9;                         // 0..1023
        int tok = mt * 16 + (lane & 15);
        int b = tok >> 10, hw = tok & 1023;
        int d0 = kc * 32 + (lane >> 4) * 8;
        const float* src = x + (size_t)b * 262144 + (size_t)d0 * 1024 + hw;
        h8 hi; float tmp[8];
        #pragma unroll
        for (int u = 0; u < 8; u++) {
            float v = src[(size_t)u * 1024];
            hi[u] = (_Float16)(v * -2.0f);
            tmp[u] = v;
        }
        *(h8*)(Ap + ((size_t)(mt * 8 + kc) * 64 + lane) * 8) = hi;
        *(float4*)(xT + (size_t)tok * 256 + d0)     = *(float4*)(&tmp[0]);
        *(float4*)(xT + (size_t)tok * 256 + d0 + 4) = *(float4*)(&tmp[4]);
    } else if (bb < 3072) {
        int g = (bb - 2048) * 256 + threadIdx.x;
        int lane = g & 63;
        int kc = (g >> 6) & 7;
        int ntp = g >> 9;                        // 0..511 global code-tile
        int n = ntp * 16 + (lane & 15);
        int d0 = kc * 32 + (lane >> 4) * 8;
        const float* src = emb + (size_t)n * EMB_DIM + d0;
        h8 hi;
        #pragma unroll
        for (int u = 0; u < 8; u++) hi[u] = (_Float16)src[u];
        // ntp = (bS<<5)|(nt<<3)|(wn<<2)|j
        int bS = ntp >> 5, nt = (ntp >> 3) & 3, wnp = (ntp >> 2) & 1, jp = ntp & 3;
        size_t off = ((size_t)bS << 17) + ((size_t)wnp << 16)
                   + (size_t)((nt * 8 + kc) * 4 + jp) * 512 + (size_t)lane * 8;
        *(h8*)(Bp + off) = hi;
    } else if (bb < 5120) {
        int k = (bb - 3072) * 4 + (threadIdx.x >> 6);
        int lane = threadIdx.x & 63;
        const float* row = emb + (size_t)k * EMB_DIM;
        float4 v = *(const float4*)(row + lane * 4);
        float s = v.x * v.x + v.y * v.y + v.z * v.z + v.w * v.w;
        #pragma unroll
        for (int m = 32; m >= 1; m >>= 1) s += __shfl_xor(s, m);
        if (lane == 0) esq[k] = s;
    } else {
        counts[(bb - 5120) * 256 + threadIdx.x] = 0.0f;
    }
}

// ---------------- k_dist: 64x512 block, 128 thr, 64 tok/wave (acc[4][4]) ------------
// Each of 2 waves computes ALL 64 tokens x its 256-code half: per t-iter 16 MFMA vs
// 4 B-loads -> 2x arithmetic intensity vs r5 (B L2 traffic 2.1GB -> 1.05GB), and the
// 1-deep B prefetch (~310cy of MFMA ahead) covers L2 latency (~200cy).
// dv = (esq+4096) - 2*dot fully in the MFMA pipe (C-init = esq+4096, A prescaled -2).
// Low 4 mantissa bits carry (nt<<2)|j; exact top-2 via v_min3/v_med3.
__global__ __launch_bounds__(128, 2)
void k_dist(const _Float16* __restrict__ Ap, const _Float16* __restrict__ Bp,
            const float* __restrict__ esq, float4* __restrict__ pairs) {
    __shared__ __align__(16) _Float16 Abuf[64 * 256];   // 32 KB; merge buf after loop
    float4* sv2 = (float4*)Abuf;                        // valid after post-loop barrier

    const int tid    = threadIdx.x;
    const int lane   = tid & 63;
    const int lane16 = lane & 15;
    const int wn     = tid >> 6;            // 0..1: B column-half
    const int bS     = blockIdx.x >> 8;     // 0..15 (slice-major: L2 reuse of Bp)
    const int bM     = blockIdx.x & 255;    // 0..255 row-block of 64 tokens
    const int m0     = bM * 64;

    // stage A tile once: 32 KB contiguous from Ap
    #pragma unroll
    for (int s = 0; s < 16; s++) {
        int idx = s * 128 + tid;
        GLD16(Ap + (size_t)bM * 16384 + (size_t)idx * 8, Abuf + idx * 8);
    }

    // preload biased esq for all (nt, j) this lane will see
    float ev[16];
    #pragma unroll
    for (int nt = 0; nt < 4; nt++)
        #pragma unroll
        for (int j = 0; j < 4; j++)
            ev[nt * 4 + j] = esq[bS * 512 + nt * 128 + wn * 64 + j * 16 + lane16] + 4096.0f;

    int b1[16], s1[16];
    #pragma unroll
    for (int r = 0; r < 16; r++) { b1[r] = 0x7f7fffff; s1[r] = 0x7f7fffff; }

    __syncthreads();   // staging barrier

    const _Float16* Bptr = Bp + (size_t)bS * 131072 + (size_t)wn * 65536 + (size_t)lane * 8;
    const _Float16* Aptr = Abuf + lane * 8;

    h8 bA[4], bB[4];
    #pragma unroll
    for (int j = 0; j < 4; j++) bA[j] = *(const h8*)(Bptr + j * 512);   // t = 0

    f4 acc[4][4];

    #pragma unroll 1
    for (int mI = 0; mI < 16; mI++) {
        const int t0 = mI * 2, t1 = t0 + 1;
        const int nt = t0 >> 3;              // t0 even -> same nt for both bodies
        const int kc0 = t0 & 7, kc1 = kc0 + 1;

        // ---- body 0: consume bA, prefetch t1 into bB ----
        {
            #pragma unroll
            for (int j = 0; j < 4; j++)
                bB[j] = *(const h8*)(Bptr + (size_t)t1 * 2048 + j * 512);
            h8 aF[4];
            #pragma unroll
            for (int i = 0; i < 4; i++)
                aF[i] = *(const h8*)(Aptr + kc0 * 512 + i * 4096);
            if (kc0 == 0) {      // chain head: C-init with biased esq
                #pragma unroll
                for (int i = 0; i < 4; i++)
                    #pragma unroll
                    for (int j = 0; j < 4; j++) {
                        const float e = ev[nt * 4 + j];
                        acc[i][j] = __builtin_amdgcn_mfma_f32_16x16x32_f16(
                                        aF[i], bA[j], (f4){e, e, e, e}, 0, 0, 0);
                    }
            } else {
                #pragma unroll
                for (int i = 0; i < 4; i++)
                    #pragma unroll
                    for (int j = 0; j < 4; j++)
                        acc[i][j] = __builtin_amdgcn_mfma_f32_16x16x32_f16(
                                        aF[i], bA[j], acc[i][j], 0, 0, 0);
            }
        }
        // ---- body 1: consume bB, prefetch t1+1 into bA ----
        {
            if (t1 < 31) {
                #pragma unroll
                for (int j = 0; j < 4; j++)
                    bA[j] = *(const h8*)(Bptr + (size_t)(t1 + 1) * 2048 + j * 512);
            }
            h8 aF[4];
            #pragma unroll
            for (int i = 0; i < 4; i++)
                aF[i] = *(const h8*)(Aptr + kc1 * 512 + i * 4096);
            #pragma unroll
            for (int i = 0; i < 4; i++)
                #pragma unroll
                for (int j = 0; j < 4; j++)
                    acc[i][j] = __builtin_amdgcn_mfma_f32_16x16x32_f16(
                                    aF[i], bB[j], acc[i][j], 0, 0, 0);

            if (kc1 == 7) {      // per-nt epilogue: pack + batched top-2, no resets
                #pragma unroll
                for (int i = 0; i < 4; i++)
                    #pragma unroll
                    for (int reg = 0; reg < 4; reg++) {
                        const int r = i * 4 + reg;
                        int c0 = (__float_as_int(acc[i][0][reg]) & ~0xF) | (nt << 2) | 0;
                        int c1 = (__float_as_int(acc[i][1][reg]) & ~0xF) | (nt << 2) | 1;
                        int c2 = (__float_as_int(acc[i][2][reg]) & ~0xF) | (nt << 2) | 2;
                        int c3 = (__float_as_int(acc[i][3][reg]) & ~0xF) | (nt << 2) | 3;
                        int m1 = imed3(b1[r], c0, c1);
                        b1[r]  = imin3(b1[r], c0, c1);
                        int m2 = imed3(b1[r], c2, c3);
                        b1[r]  = imin3(b1[r], c2, c3);
                        s1[r]  = imin3(s1[r], m1, m2);
                    }
            }
        }
    }

    __syncthreads();   // all Abuf reads done -> safe to reuse LDS as sv2

    // unpack (nt,j) codes -> full indices, then cross-lane16 exact top-2 merge
    #pragma unroll
    for (int i = 0; i < 4; i++) {
        #pragma unroll
        for (int reg = 0; reg < 4; reg++) {
            const int rr = i * 4 + reg;
            int bv = b1[rr], sv = s1[rr];
            int bki = bS * 512 + ((bv >> 2) & 3) * 128 + (bv & 3) * 16 + wn * 64 + lane16;
            int ski = bS * 512 + ((sv >> 2) & 3) * 128 + (sv & 3) * 16 + wn * 64 + lane16;
            #pragma unroll
            for (int mask = 1; mask <= 8; mask <<= 1) {
                int ov  = __shfl_xor(bv, mask);  int oki  = __shfl_xor(bki, mask);
                int ov2 = __shfl_xor(sv, mask);  int oki2 = __shfl_xor(ski, mask);
                if (ov < bv || (ov == bv && oki < bki)) {
                    int ns = bv; int nsi = bki;
                    if (ov2 < ns) { ns = ov2; nsi = oki2; }
                    bv = ov; bki = oki; sv = ns; ski = nsi;
                } else if (ov < sv) { sv = ov; ski = oki; }
            }
            if (lane16 == 0) {
                int r = i * 16 + ((lane >> 4) << 2) + reg;   // token-row within 64
                sv2[wn * 64 + r] = make_float4(__int_as_float(bv), __int_as_float(bki),
                                               __int_as_float(sv), __int_as_float(ski));
            }
        }
    }
    __syncthreads();
    if (tid < 64) {
        float4 A = sv2[tid], C = sv2[64 + tid];
        float a1 = A.x, a2 = A.z, c1 = C.x, c2 = C.z;
        int a1i = __float_as_int(A.y), a2i = __float_as_int(A.w);
        int c1i = __float_as_int(C.y), c2i = __float_as_int(C.w);
        float b, s; int bi, si;
        if (c1 < a1 || (c1 == a1 && c1i < a1i)) {
            b = c1; bi = c1i; s = a1; si = a1i;
            if (c2 < s) { s = c2; si = c2i; }
        } else {
            b = a1; bi = a1i; s = a2; si = a2i;
            if (c1 < s) { s = c1; si = c1i; }
        }
        pairs[(size_t)(m0 + tid) * NSLICE + bS] = make_float4(b, __int_as_float(bi), s, __int_as_float(si));
    }
}

// ---------------- k_rq: fused refine (exact fp32 argmin) + coalesced q_st + loss ----
// Block = 64 consecutive tokens, 512 threads (8 waves x 8 tokens each).
__global__ __launch_bounds__(512)
void k_rq(const float4* __restrict__ pairs, const float* __restrict__ xT,
          const float* __restrict__ emb, const float* __restrict__ esq,
          const float* __restrict__ x,
          int* __restrict__ idx_i32, float* __restrict__ out_idxf,
          float* __restrict__ counts, float* __restrict__ out_qst,
          float* __restrict__ loss_parts) {
    __shared__ float Q[64 * 257];   // winner rows, stride 257
    __shared__ float wsum[8];
    int tid = threadIdx.x;
    int lane = tid & 63, wid = tid >> 6;
    int tok0 = blockIdx.x * 64;
    int b = tok0 >> 10, hw0 = tok0 & 1023;

    for (int s = 0; s < 8; s++) {
        int tl = wid * 8 + s;
        int tok = tok0 + tl;
        float4 p = (lane < NSLICE) ? pairs[(size_t)tok * NSLICE + lane]
                                   : make_float4(3.4e38f, __int_as_float(0x7fffffff),
                                                 3.4e38f, __int_as_float(0x7fffffff));
        float v1 = p.x, v2 = p.z;
        int i1 = __float_as_int(p.y), i2 = __float_as_int(p.w);

        float bv = v1; int bi = i1;
        #pragma unroll
        for (int mask = 1; mask <= 32; mask <<= 1) {
            float ov = __shfl_xor(bv, mask); int oi = __shfl_xor(bi, mask);
            if (ov < bv || (ov == bv && oi < bi)) { bv = ov; bi = oi; }
        }
        float thresh = bv + MARGIN;
        float4 xv = *(const float4*)(xT + (size_t)tok * 256 + lane * 4);

        unsigned long long m1 = __ballot(v1 <= thresh);
        unsigned long long m2 = __ballot(v2 <= thresh);
        float bestd = 3.4e38f; int besti = 0x7fffffff;
        while (m1 | m2) {
            int k;
            if (m1) { int l = __ffsll(m1) - 1; m1 &= m1 - 1; k = __shfl(i1, l); }
            else    { int l = __ffsll(m2) - 1; m2 &= m2 - 1; k = __shfl(i2, l); }
            float4 e4 = *(const float4*)(emb + (size_t)k * EMB_DIM + lane * 4);
            float d = xv.x * e4.x + xv.y * e4.y + xv.z * e4.z + xv.w * e4.w;
            #pragma unroll
            for (int mask = 1; mask <= 32; mask <<= 1) d += __shfl_xor(d, mask);
            float dist = esq[k] - 2.0f * d;
            if (dist < bestd || (dist == bestd && k < besti)) { bestd = dist; besti = k; }
        }
        // stash winner row into LDS
        float4 e4 = *(const float4*)(emb + (size_t)besti * EMB_DIM + lane * 4);
        float* q = Q + tl * 257 + lane * 4;
        q[0] = e4.x; q[1] = e4.y; q[2] = e4.z; q[3] = e4.w;
        if (lane == 0) {
            idx_i32[tok] = besti;
            out_idxf[tok] = (float)besti;
            atomicAdd(&counts[besti], 1.0f);
        }
    }
    __syncthreads();

    // phase 2: coalesced NCHW straight-through write + loss
    int lane16 = tid & 15, dg = tid >> 4;      // dg 0..31
    int hwoff = lane16 * 4;
    float sq = 0.0f;
    #pragma unroll 2
    for (int it = 0; it < 8; it++) {
        int d = it * 32 + dg;
        const float* xb = x + (size_t)b * 262144 + (size_t)d * 1024 + hw0 + hwoff;
        float4 xv = *(const float4*)xb;
        float q0 = Q[(hwoff + 0) * 257 + d];
        float q1 = Q[(hwoff + 1) * 257 + d];
        float q2 = Q[(hwoff + 2) * 257 + d];
        float q3 = Q[(hwoff + 3) * 257 + d];
        float d0 = q0 - xv.x, d1 = q1 - xv.y, d2 = q2 - xv.z, d3 = q3 - xv.w;
        float4 o; o.x = xv.x + d0; o.y = xv.y + d1; o.z = xv.z + d2; o.w = xv.w + d3;
        *(float4*)(out_qst + (size_t)b * 262144 + (size_t)d * 1024 + hw0 + hwoff) = o;
        sq += d0 * d0 + d1 * d1 + d2 * d2 + d3 * d3;
    }
    #pragma unroll
    for (int m = 32; m >= 1; m >>= 1) sq += __shfl_xor(sq, m);
    if (lane == 0) wsum[wid] = sq;
    __syncthreads();
    if (tid == 0) {
        float t = 0.0f;
        #pragma unroll
        for (int u = 0; u < 8; u++) t += wsum[u];
        loss_parts[blockIdx.x] = t;
    }
}

// ---------------- k_ivt_stats: prefix sum -> offsets/gcur + n/perplexity/loss -------
__global__ __launch_bounds__(256)
void k_ivt_stats(const float* __restrict__ counts,
                 const float* __restrict__ cs, const float* __restrict__ loss_parts,
                 int* __restrict__ offsets, int* __restrict__ gcur,
                 float* __restrict__ n_out, float* __restrict__ out) {
    __shared__ int part[256];
    int t = threadIdx.x;
    int base = t * 32;
    int loc[32]; int s = 0;
    #pragma unroll
    for (int u = 0; u < 32; u++) { loc[u] = s; s += (int)counts[base + u]; }
    part[t] = s;
    __syncthreads();
    for (int off = 1; off < 256; off <<= 1) {
        int add = (t >= off) ? part[t - off] : 0;
        __syncthreads();
        part[t] += add;
        __syncthreads();
    }
    int excl = part[t] - s;
    #pragma unroll
    for (int u = 0; u < 32; u++) {
        int o = excl + loc[u];
        offsets[base + u] = o;
        gcur[base + u] = o;
    }

    float s1 = 0.0f, s2 = 0.0f;
    for (int k = t; k < NUM_EMB; k += 256) {
        float c = counts[k];
        s1 += cs[k] * DECAY + OMD * c;
        float pb = c / (float)NTOK;
        s2 += pb * logf(pb + 1e-10f);
    }
    float s3 = loss_parts[t];
    #pragma unroll
    for (int m = 32; m >= 1; m >>= 1) {
        s1 += __shfl_xor(s1, m);
        s2 += __shfl_xor(s2, m);
        s3 += __shfl_xor(s3, m);
    }
    __shared__ float w1[4], w2[4], w3[4];
    int lane = t & 63, wid = t >> 6;
    if (lane == 0) { w1[wid] = s1; w2[wid] = s2; w3[wid] = s3; }
    __syncthreads();
    if (t == 0) {
        float n  = w1[0] + w1[1] + w1[2] + w1[3];
        float e2 = w2[0] + w2[1] + w2[2] + w2[3];
        float ls = w3[0] + w3[1] + w3[2] + w3[3];
        n_out[0] = n;
        out[4194305] = expf(-e2);                 // perplexity
        out[0] = COMMIT * ls / (float)QELEMS;     // loss
    }
}

// ---------------- k_scatter: parallel toklist build (device-scope atomics) ----------
// List order within a code differs from any serial order; consumers only sum -> OK.
__global__ __launch_bounds__(256)
void k_scatter(const int* __restrict__ idx_i32, int* __restrict__ gcur,
               int* __restrict__ toklist) {
    int n = blockIdx.x * 256 + threadIdx.x;
    int k = idx_i32[n];
    int p = atomicAdd(&gcur[k], 1);
    toklist[p] = n;
}

// ---------------- k_dw_final: 2-wave per-code dw row-sum + EMA outputs --------------
__global__ __launch_bounds__(128)
void k_dw_final(const float* __restrict__ xT, const float* __restrict__ counts,
                const int* __restrict__ offsets, const int* __restrict__ toklist,
                const float* __restrict__ cs, const float* __restrict__ emaw,
                const float* __restrict__ n_in,
                float* __restrict__ out_emb, float* __restrict__ out_cs,
                float* __restrict__ out_emaw) {
    __shared__ float4 sbuf[2][64];
    int k = blockIdx.x;
    int lane = threadIdx.x & 63, wid = threadIdx.x >> 6;
    int c = (int)counts[k];
    int off = offsets[k];
    float a0 = 0, a1 = 0, a2 = 0, a3 = 0;
    for (int t = wid; t < c; t += 2) {
        int tok = toklist[off + t];
        float4 v = *(const float4*)(xT + (size_t)tok * 256 + lane * 4);
        a0 += v.x; a1 += v.y; a2 += v.z; a3 += v.w;
    }
    sbuf[wid][lane] = make_float4(a0, a1, a2, a3);
    __syncthreads();
    if (wid == 0) {
        float4 p0 = sbuf[0][lane], p1 = sbuf[1][lane];
        a0 = p0.x + p1.x; a1 = p0.y + p1.y; a2 = p0.z + p1.z; a3 = p0.w + p1.w;
        float n = n_in[0];
        float pre  = cs[k] * DECAY + OMD * counts[k];
        float cssm = (pre + EPS_) / (n + (float)NUM_EMB * EPS_) * n;
        size_t o = (size_t)k * EMB_DIM + lane * 4;
        float4 ew = *(const float4*)(emaw + o);
        float4 wv;
        wv.x = ew.x * DECAY + OMD * a0;
        wv.y = ew.y * DECAY + OMD * a1;
        wv.z = ew.z * DECAY + OMD * a2;
        wv.w = ew.w * DECAY + OMD * a3;
        *(float4*)(out_emaw + o) = wv;
        float4 obv; obv.x = wv.x / cssm; obv.y = wv.y / cssm;
        obv.z = wv.z / cssm; obv.w = wv.w / cssm;
        *(float4*)(out_emb + o) = obv;
        if (lane == 0) out_cs[k] = cssm;
    }
}

extern "C" void kernel_launch(void* const* d_in, const int* in_sizes, int n_in,
                              void* d_out, int out_size, void* d_ws, size_t ws_size,
                              hipStream_t stream) {
    const float* x    = (const float*)d_in[0];   // [16,256,32,32]
    const float* emb  = (const float*)d_in[1];   // [8192,256]
    const float* cs   = (const float*)d_in[2];   // [8192]
    const float* emaw = (const float*)d_in[3];   // [8192,256]
    float* out = (float*)d_out;

    // workspace layout (bytes)
    char* W = (char*)d_ws;
    _Float16* Ap      = (_Float16*)(W);             //  8,388,608
    _Float16* Bp      = (_Float16*)(W + 8388608);   //  4,194,304
    float*  xT        = (float*) (W + 12582912);    // 16,777,216
    float4* pairs     = (float4*)(W + 29360128);    //  4,194,304
    float* esq        = (float*) (W + 33554432);    //     32,768
    float* counts     = (float*) (W + 33587200);    //     32,768
    float* loss_parts = (float*) (W + 33619968);    //      1,024
    float* n_scal     = (float*) (W + 33621248);    //          4
    int*   offsets    = (int*)   (W + 33621252);    //     32,768
    int*   toklist    = (int*)   (W + 33654020);    //     65,536
    int*   idx_i32    = (int*)   (W + 33719556);    //     65,536
    int*   gcur       = (int*)   (W + 33785092);    //     32,768

    k_prep     <<<5152, 256, 0, stream>>>(x, emb, Ap, Bp, xT, esq, counts);
    k_dist     <<<4096, 128, 0, stream>>>(Ap, Bp, esq, pairs);
    k_rq       <<<256, 512, 0, stream>>>(pairs, xT, emb, esq, x, idx_i32,
                                         out + 8396802, counts, out + 1, loss_parts);
    k_ivt_stats<<<1, 256, 0, stream>>>(counts, cs, loss_parts,
                                       offsets, gcur, n_scal, out);
    k_scatter  <<<64, 256, 0, stream>>>(idx_i32, gcur, toklist);
    k_dw_final <<<NUM_EMB, 128, 0, stream>>>(xT, counts, offsets, toklist, cs, emaw,
                                             n_scal, out + 4194306, out + 6291458,
                                             out + 6299650);
}

// Round 7
// 282.960 us; speedup vs baseline: 1.0404x; 1.0404x over previous
//
#include <hip/hip_runtime.h>
#include <hip/hip_bf16.h>
#include <math.h>

#define NUM_EMB 8192
#define EMB_DIM 256
#define NTOK    16384      // 16 * 32 * 32
#define HW      1024
#define QELEMS  4194304    // 16 * 256 * 1024
#define DECAY   0.99f
#define OMD     0.01f
#define COMMIT  0.25f
#define EPS_    1e-5f
#define MARGIN  0.6f
#define NSLICE  16         // codes per slice = 512

typedef _Float16 h8 __attribute__((ext_vector_type(8)));
typedef float    f4 __attribute__((ext_vector_type(4)));

#define GLD16(gptr, lptr) \
  __builtin_amdgcn_global_load_lds((const __attribute__((address_space(1))) void*)(gptr), \
                                   (__attribute__((address_space(3))) void*)(lptr), 16, 0, 0)

__device__ __forceinline__ int imin3(int a, int b, int c) {
    int d; asm("v_min3_i32 %0, %1, %2, %3" : "=v"(d) : "v"(a), "v"(b), "v"(c)); return d;
}
__device__ __forceinline__ int imed3(int a, int b, int c) {
    int d; asm("v_med3_i32 %0, %1, %2, %3" : "=v"(d) : "v"(a), "v"(b), "v"(c)); return d;
}

// ---------------- k_prep: x->Ap(-2x, f16)+xT(f32), emb->Bp(f16), esq, zero counts --
// Ap is pre-scaled by -2 (exact pow2 f16 scale) so k_dist's MFMA accumulates -2*dot
// directly on top of a C-init of (esq+4096). Ap feeds ONLY k_dist; xT stays exact.
// Bp layout is read-order-major for k_dist: [bS][wn][t=nt*8+kc][j][lane][8] so the
// inner-loop B address is base + t*2048 elems with j folded into the load imm.
__global__ __launch_bounds__(256)
void k_prep(const float* __restrict__ x, const float* __restrict__ emb,
            _Float16* __restrict__ Ap, _Float16* __restrict__ Bp,
            float* __restrict__ xT, float* __restrict__ esq,
            float* __restrict__ counts) {
    int bb = blockIdx.x;
    if (bb < 2048) {
        int g = bb * 256 + threadIdx.x;
        int lane = g & 63;
        int kc = (g >> 6) & 7;
        int mt = g >> 9;                         // 0..1023
        int tok = mt * 16 + (lane & 15);
        int b = tok >> 10, hw = tok & 1023;
        int d0 = kc * 32 + (lane >> 4) * 8;
        const float* src = x + (size_t)b * 262144 + (size_t)d0 * 1024 + hw;
        h8 hi; float tmp[8];
        #pragma unroll
        for (int u = 0; u < 8; u++) {
            float v = src[(size_t)u * 1024];
            hi[u] = (_Float16)(v * -2.0f);
            tmp[u] = v;
        }
        *(h8*)(Ap + ((size_t)(mt * 8 + kc) * 64 + lane) * 8) = hi;
        *(float4*)(xT + (size_t)tok * 256 + d0)     = *(float4*)(&tmp[0]);
        *(float4*)(xT + (size_t)tok * 256 + d0 + 4) = *(float4*)(&tmp[4]);
    } else if (bb < 3072) {
        int g = (bb - 2048) * 256 + threadIdx.x;
        int lane = g & 63;
        int kc = (g >> 6) & 7;
        int ntp = g >> 9;                        // 0..511 global code-tile
        int n = ntp * 16 + (lane & 15);
        int d0 = kc * 32 + (lane >> 4) * 8;
        const float* src = emb + (size_t)n * EMB_DIM + d0;
        h8 hi;
        #pragma unroll
        for (int u = 0; u < 8; u++) hi[u] = (_Float16)src[u];
        // ntp = (bS<<5)|(nt<<3)|(wn<<2)|j
        int bS = ntp >> 5, nt = (ntp >> 3) & 3, wnp = (ntp >> 2) & 1, jp = ntp & 3;
        size_t off = ((size_t)bS << 17) + ((size_t)wnp << 16)
                   + (size_t)((nt * 8 + kc) * 4 + jp) * 512 + (size_t)lane * 8;
        *(h8*)(Bp + off) = hi;
    } else if (bb < 5120) {
        int k = (bb - 3072) * 4 + (threadIdx.x >> 6);
        int lane = threadIdx.x & 63;
        const float* row = emb + (size_t)k * EMB_DIM;
        float4 v = *(const float4*)(row + lane * 4);
        float s = v.x * v.x + v.y * v.y + v.z * v.z + v.w * v.w;
        #pragma unroll
        for (int m = 32; m >= 1; m >>= 1) s += __shfl_xor(s, m);
        if (lane == 0) esq[k] = s;
    } else {
        counts[(bb - 5120) * 256 + threadIdx.x] = 0.0f;
    }
}

// ---------------- k_dist: 128x512 block, 512 thr / 8 waves, r4 per-wave loop --------
// Per-wave loop identical to the proven 99.4us r4 kernel (acc[2][4], 1-deep ping-pong
// B prefetch, bias-in-C, min3/med3 top-2). Block carries 128 tokens / 64KB LDS so
// 2 blocks/CU = 16 waves/CU (vs 12.8) and block B traffic amortizes over 2x tokens.
// dv = (esq+4096) - 2*dot fully in the MFMA pipe; low 4 mantissa bits = (nt<<2)|j.
__global__ __launch_bounds__(512, 4)
void k_dist(const _Float16* __restrict__ Ap, const _Float16* __restrict__ Bp,
            const float* __restrict__ esq, float4* __restrict__ pairs) {
    __shared__ __align__(16) _Float16 Abuf[128 * 256];  // 64 KB; merge buf after loop
    float4* sv2 = (float4*)Abuf;                        // valid after post-loop barrier

    const int tid    = threadIdx.x;
    const int lane   = tid & 63;
    const int lane16 = lane & 15;
    const int w      = tid >> 6;
    const int wm     = w >> 1, wn = w & 1;  // wm 0..3: token quarter, wn 0..1: B half
    const int bS     = blockIdx.x >> 7;     // 0..15 (slice-major: L2 reuse of Bp)
    const int bM     = blockIdx.x & 127;    // 0..127 row-block of 128 tokens
    const int m0     = bM * 128;

    // stage A tile once: 64 KB contiguous from Ap
    #pragma unroll
    for (int s = 0; s < 8; s++) {
        int idx = s * 512 + tid;
        GLD16(Ap + (size_t)bM * 32768 + (size_t)idx * 8, Abuf + idx * 8);
    }

    // preload biased esq for all (nt, j) this lane will see
    float ev[16];
    #pragma unroll
    for (int nt = 0; nt < 4; nt++)
        #pragma unroll
        for (int j = 0; j < 4; j++)
            ev[nt * 4 + j] = esq[bS * 512 + nt * 128 + wn * 64 + j * 16 + lane16] + 4096.0f;

    int b1[8], s1[8];
    #pragma unroll
    for (int r = 0; r < 8; r++) { b1[r] = 0x7f7fffff; s1[r] = 0x7f7fffff; }

    __syncthreads();   // staging barrier

    const _Float16* Bptr = Bp + (size_t)bS * 131072 + (size_t)wn * 65536 + (size_t)lane * 8;
    const _Float16* Aptr = Abuf + wm * 8192 + lane * 8;

    h8 bA[4], bB[4];
    #pragma unroll
    for (int j = 0; j < 4; j++) bA[j] = *(const h8*)(Bptr + j * 512);   // t = 0

    f4 acc[2][4];

    #pragma unroll 1
    for (int mI = 0; mI < 16; mI++) {
        const int t0 = mI * 2, t1 = t0 + 1;
        const int nt = t0 >> 3;              // t0 even -> same nt for both bodies
        const int kc0 = t0 & 7, kc1 = kc0 + 1;

        // ---- body 0: consume bA, prefetch t1 into bB ----
        {
            #pragma unroll
            for (int j = 0; j < 4; j++)
                bB[j] = *(const h8*)(Bptr + (size_t)t1 * 2048 + j * 512);
            h8 aF[2];
            #pragma unroll
            for (int i = 0; i < 2; i++)
                aF[i] = *(const h8*)(Aptr + kc0 * 512 + i * 4096);
            if (kc0 == 0) {      // chain head: C-init with biased esq
                #pragma unroll
                for (int i = 0; i < 2; i++)
                    #pragma unroll
                    for (int j = 0; j < 4; j++) {
                        const float e = ev[nt * 4 + j];
                        acc[i][j] = __builtin_amdgcn_mfma_f32_16x16x32_f16(
                                        aF[i], bA[j], (f4){e, e, e, e}, 0, 0, 0);
                    }
            } else {
                #pragma unroll
                for (int i = 0; i < 2; i++)
                    #pragma unroll
                    for (int j = 0; j < 4; j++)
                        acc[i][j] = __builtin_amdgcn_mfma_f32_16x16x32_f16(
                                        aF[i], bA[j], acc[i][j], 0, 0, 0);
            }
        }
        // ---- body 1: consume bB, prefetch t1+1 into bA ----
        {
            if (t1 < 31) {
                #pragma unroll
                for (int j = 0; j < 4; j++)
                    bA[j] = *(const h8*)(Bptr + (size_t)(t1 + 1) * 2048 + j * 512);
            }
            h8 aF[2];
            #pragma unroll
            for (int i = 0; i < 2; i++)
                aF[i] = *(const h8*)(Aptr + kc1 * 512 + i * 4096);
            #pragma unroll
            for (int i = 0; i < 2; i++)
                #pragma unroll
                for (int j = 0; j < 4; j++)
                    acc[i][j] = __builtin_amdgcn_mfma_f32_16x16x32_f16(
                                    aF[i], bB[j], acc[i][j], 0, 0, 0);

            if (kc1 == 7) {      // per-nt epilogue: pack + batched top-2, no resets
                #pragma unroll
                for (int i = 0; i < 2; i++)
                    #pragma unroll
                    for (int reg = 0; reg < 4; reg++) {
                        const int r = i * 4 + reg;
                        int c0 = (__float_as_int(acc[i][0][reg]) & ~0xF) | (nt << 2) | 0;
                        int c1 = (__float_as_int(acc[i][1][reg]) & ~0xF) | (nt << 2) | 1;
                        int c2 = (__float_as_int(acc[i][2][reg]) & ~0xF) | (nt << 2) | 2;
                        int c3 = (__float_as_int(acc[i][3][reg]) & ~0xF) | (nt << 2) | 3;
                        int m1 = imed3(b1[r], c0, c1);
                        b1[r]  = imin3(b1[r], c0, c1);
                        int m2 = imed3(b1[r], c2, c3);
                        b1[r]  = imin3(b1[r], c2, c3);
                        s1[r]  = imin3(s1[r], m1, m2);
                    }
            }
        }
    }

    __syncthreads();   // all Abuf reads done -> safe to reuse LDS as sv2

    // unpack (nt,j) codes -> full indices, then cross-lane16 exact top-2 merge
    #pragma unroll
    for (int i = 0; i < 2; i++) {
        #pragma unroll
        for (int reg = 0; reg < 4; reg++) {
            const int rr = i * 4 + reg;
            int bv = b1[rr], sv = s1[rr];
            int bki = bS * 512 + ((bv >> 2) & 3) * 128 + (bv & 3) * 16 + wn * 64 + lane16;
            int ski = bS * 512 + ((sv >> 2) & 3) * 128 + (sv & 3) * 16 + wn * 64 + lane16;
            #pragma unroll
            for (int mask = 1; mask <= 8; mask <<= 1) {
                int ov  = __shfl_xor(bv, mask);  int oki  = __shfl_xor(bki, mask);
                int ov2 = __shfl_xor(sv, mask);  int oki2 = __shfl_xor(ski, mask);
                if (ov < bv || (ov == bv && oki < bki)) {
                    int ns = bv; int nsi = bki;
                    if (ov2 < ns) { ns = ov2; nsi = oki2; }
                    bv = ov; bki = oki; sv = ns; ski = nsi;
                } else if (ov < sv) { sv = ov; ski = oki; }
            }
            if (lane16 == 0) {
                int r = (wm * 2 + i) * 16 + ((lane >> 4) << 2) + reg; // row within 128
                sv2[wn * 128 + r] = make_float4(__int_as_float(bv), __int_as_float(bki),
                                                __int_as_float(sv), __int_as_float(ski));
            }
        }
    }
    __syncthreads();
    if (tid < 128) {
        float4 A = sv2[tid], C = sv2[128 + tid];
        float a1 = A.x, a2 = A.z, c1 = C.x, c2 = C.z;
        int a1i = __float_as_int(A.y), a2i = __float_as_int(A.w);
        int c1i = __float_as_int(C.y), c2i = __float_as_int(C.w);
        float b, s; int bi, si;
        if (c1 < a1 || (c1 == a1 && c1i < a1i)) {
            b = c1; bi = c1i; s = a1; si = a1i;
            if (c2 < s) { s = c2; si = c2i; }
        } else {
            b = a1; bi = a1i; s = a2; si = a2i;
            if (c1 < s) { s = c1; si = c1i; }
        }
        pairs[(size_t)(m0 + tid) * NSLICE + bS] = make_float4(b, __int_as_float(bi), s, __int_as_float(si));
    }
}

// ---------------- k_rq: fused refine (exact fp32 argmin) + coalesced q_st + loss ----
// Block = 64 consecutive tokens, 512 threads (8 waves x 8 tokens each).
__global__ __launch_bounds__(512)
void k_rq(const float4* __restrict__ pairs, const float* __restrict__ xT,
          const float* __restrict__ emb, const float* __restrict__ esq,
          const float* __restrict__ x,
          int* __restrict__ idx_i32, float* __restrict__ out_idxf,
          float* __restrict__ counts, float* __restrict__ out_qst,
          float* __restrict__ loss_parts) {
    __shared__ float Q[64 * 257];   // winner rows, stride 257
    __shared__ float wsum[8];
    int tid = threadIdx.x;
    int lane = tid & 63, wid = tid >> 6;
    int tok0 = blockIdx.x * 64;
    int b = tok0 >> 10, hw0 = tok0 & 1023;

    for (int s = 0; s < 8; s++) {
        int tl = wid * 8 + s;
        int tok = tok0 + tl;
        float4 p = (lane < NSLICE) ? pairs[(size_t)tok * NSLICE + lane]
                                   : make_float4(3.4e38f, __int_as_float(0x7fffffff),
                                                 3.4e38f, __int_as_float(0x7fffffff));
        float v1 = p.x, v2 = p.z;
        int i1 = __float_as_int(p.y), i2 = __float_as_int(p.w);

        float bv = v1; int bi = i1;
        #pragma unroll
        for (int mask = 1; mask <= 32; mask <<= 1) {
            float ov = __shfl_xor(bv, mask); int oi = __shfl_xor(bi, mask);
            if (ov < bv || (ov == bv && oi < bi)) { bv = ov; bi = oi; }
        }
        float thresh = bv + MARGIN;
        float4 xv = *(const float4*)(xT + (size_t)tok * 256 + lane * 4);

        unsigned long long m1 = __ballot(v1 <= thresh);
        unsigned long long m2 = __ballot(v2 <= thresh);
        float bestd = 3.4e38f; int besti = 0x7fffffff;
        while (m1 | m2) {
            int k;
            if (m1) { int l = __ffsll(m1) - 1; m1 &= m1 - 1; k = __shfl(i1, l); }
            else    { int l = __ffsll(m2) - 1; m2 &= m2 - 1; k = __shfl(i2, l); }
            float4 e4 = *(const float4*)(emb + (size_t)k * EMB_DIM + lane * 4);
            float d = xv.x * e4.x + xv.y * e4.y + xv.z * e4.z + xv.w * e4.w;
            #pragma unroll
            for (int mask = 1; mask <= 32; mask <<= 1) d += __shfl_xor(d, mask);
            float dist = esq[k] - 2.0f * d;
            if (dist < bestd || (dist == bestd && k < besti)) { bestd = dist; besti = k; }
        }
        // stash winner row into LDS
        float4 e4 = *(const float4*)(emb + (size_t)besti * EMB_DIM + lane * 4);
        float* q = Q + tl * 257 + lane * 4;
        q[0] = e4.x; q[1] = e4.y; q[2] = e4.z; q[3] = e4.w;
        if (lane == 0) {
            idx_i32[tok] = besti;
            out_idxf[tok] = (float)besti;
            atomicAdd(&counts[besti], 1.0f);
        }
    }
    __syncthreads();

    // phase 2: coalesced NCHW straight-through write + loss
    int lane16 = tid & 15, dg = tid >> 4;      // dg 0..31
    int hwoff = lane16 * 4;
    float sq = 0.0f;
    #pragma unroll 2
    for (int it = 0; it < 8; it++) {
        int d = it * 32 + dg;
        const float* xb = x + (size_t)b * 262144 + (size_t)d * 1024 + hw0 + hwoff;
        float4 xv = *(const float4*)xb;
        float q0 = Q[(hwoff + 0) * 257 + d];
        float q1 = Q[(hwoff + 1) * 257 + d];
        float q2 = Q[(hwoff + 2) * 257 + d];
        float q3 = Q[(hwoff + 3) * 257 + d];
        float d0 = q0 - xv.x, d1 = q1 - xv.y, d2 = q2 - xv.z, d3 = q3 - xv.w;
        float4 o; o.x = xv.x + d0; o.y = xv.y + d1; o.z = xv.z + d2; o.w = xv.w + d3;
        *(float4*)(out_qst + (size_t)b * 262144 + (size_t)d * 1024 + hw0 + hwoff) = o;
        sq += d0 * d0 + d1 * d1 + d2 * d2 + d3 * d3;
    }
    #pragma unroll
    for (int m = 32; m >= 1; m >>= 1) sq += __shfl_xor(sq, m);
    if (lane == 0) wsum[wid] = sq;
    __syncthreads();
    if (tid == 0) {
        float t = 0.0f;
        #pragma unroll
        for (int u = 0; u < 8; u++) t += wsum[u];
        loss_parts[blockIdx.x] = t;
    }
}

// ---------------- k_ivt_stats: prefix sum -> offsets/gcur + n/perplexity/loss -------
__global__ __launch_bounds__(256)
void k_ivt_stats(const float* __restrict__ counts,
                 const float* __restrict__ cs, const float* __restrict__ loss_parts,
                 int* __restrict__ offsets, int* __restrict__ gcur,
                 float* __restrict__ n_out, float* __restrict__ out) {
    __shared__ int part[256];
    int t = threadIdx.x;
    int base = t * 32;
    int loc[32]; int s = 0;
    #pragma unroll
    for (int u = 0; u < 32; u++) { loc[u] = s; s += (int)counts[base + u]; }
    part[t] = s;
    __syncthreads();
    for (int off = 1; off < 256; off <<= 1) {
        int add = (t >= off) ? part[t - off] : 0;
        __syncthreads();
        part[t] += add;
        __syncthreads();
    }
    int excl = part[t] - s;
    #pragma unroll
    for (int u = 0; u < 32; u++) {
        int o = excl + loc[u];
        offsets[base + u] = o;
        gcur[base + u] = o;
    }

    float s1 = 0.0f, s2 = 0.0f;
    for (int k = t; k < NUM_EMB; k += 256) {
        float c = counts[k];
        s1 += cs[k] * DECAY + OMD * c;
        float pb = c / (float)NTOK;
        s2 += pb * logf(pb + 1e-10f);
    }
    float s3 = loss_parts[t];
    #pragma unroll
    for (int m = 32; m >= 1; m >>= 1) {
        s1 += __shfl_xor(s1, m);
        s2 += __shfl_xor(s2, m);
        s3 += __shfl_xor(s3, m);
    }
    __shared__ float w1[4], w2[4], w3[4];
    int lane = t & 63, wid = t >> 6;
    if (lane == 0) { w1[wid] = s1; w2[wid] = s2; w3[wid] = s3; }
    __syncthreads();
    if (t == 0) {
        float n  = w1[0] + w1[1] + w1[2] + w1[3];
        float e2 = w2[0] + w2[1] + w2[2] + w2[3];
        float ls = w3[0] + w3[1] + w3[2] + w3[3];
        n_out[0] = n;
        out[4194305] = expf(-e2);                 // perplexity
        out[0] = COMMIT * ls / (float)QELEMS;     // loss
    }
}

// ---------------- k_scatter: parallel toklist build (device-scope atomics) ----------
// List order within a code differs from any serial order; consumers only sum -> OK.
__global__ __launch_bounds__(256)
void k_scatter(const int* __restrict__ idx_i32, int* __restrict__ gcur,
               int* __restrict__ toklist) {
    int n = blockIdx.x * 256 + threadIdx.x;
    int k = idx_i32[n];
    int p = atomicAdd(&gcur[k], 1);
    toklist[p] = n;
}

// ---------------- k_dw_final: 2-wave per-code dw row-sum + EMA outputs --------------
__global__ __launch_bounds__(128)
void k_dw_final(const float* __restrict__ xT, const float* __restrict__ counts,
                const int* __restrict__ offsets, const int* __restrict__ toklist,
                const float* __restrict__ cs, const float* __restrict__ emaw,
                const float* __restrict__ n_in,
                float* __restrict__ out_emb, float* __restrict__ out_cs,
                float* __restrict__ out_emaw) {
    __shared__ float4 sbuf[2][64];
    int k = blockIdx.x;
    int lane = threadIdx.x & 63, wid = threadIdx.x >> 6;
    int c = (int)counts[k];
    int off = offsets[k];
    float a0 = 0, a1 = 0, a2 = 0, a3 = 0;
    for (int t = wid; t < c; t += 2) {
        int tok = toklist[off + t];
        float4 v = *(const float4*)(xT + (size_t)tok * 256 + lane * 4);
        a0 += v.x; a1 += v.y; a2 += v.z; a3 += v.w;
    }
    sbuf[wid][lane] = make_float4(a0, a1, a2, a3);
    __syncthreads();
    if (wid == 0) {
        float4 p0 = sbuf[0][lane], p1 = sbuf[1][lane];
        a0 = p0.x + p1.x; a1 = p0.y + p1.y; a2 = p0.z + p1.z; a3 = p0.w + p1.w;
        float n = n_in[0];
        float pre  = cs[k] * DECAY + OMD * counts[k];
        float cssm = (pre + EPS_) / (n + (float)NUM_EMB * EPS_) * n;
        size_t o = (size_t)k * EMB_DIM + lane * 4;
        float4 ew = *(const float4*)(emaw + o);
        float4 wv;
        wv.x = ew.x * DECAY + OMD * a0;
        wv.y = ew.y * DECAY + OMD * a1;
        wv.z = ew.z * DECAY + OMD * a2;
        wv.w = ew.w * DECAY + OMD * a3;
        *(float4*)(out_emaw + o) = wv;
        float4 obv; obv.x = wv.x / cssm; obv.y = wv.y / cssm;
        obv.z = wv.z / cssm; obv.w = wv.w / cssm;
        *(float4*)(out_emb + o) = obv;
        if (lane == 0) out_cs[k] = cssm;
    }
}

extern "C" void kernel_launch(void* const* d_in, const int* in_sizes, int n_in,
                              void* d_out, int out_size, void* d_ws, size_t ws_size,
                              hipStream_t stream) {
    const float* x    = (const float*)d_in[0];   // [16,256,32,32]
    const float* emb  = (const float*)d_in[1];   // [8192,256]
    const float* cs   = (const float*)d_in[2];   // [8192]
    const float* emaw = (const float*)d_in[3];   // [8192,256]
    float* out = (float*)d_out;

    // workspace layout (bytes)
    char* W = (char*)d_ws;
    _Float16* Ap      = (_Float16*)(W);             //  8,388,608
    _Float16* Bp      = (_Float16*)(W + 8388608);   //  4,194,304
    float*  xT        = (float*) (W + 12582912);    // 16,777,216
    float4* pairs     = (float4*)(W + 29360128);    //  4,194,304
    float* esq        = (float*) (W + 33554432);    //     32,768
    float* counts     = (float*) (W + 33587200);    //     32,768
    float* loss_parts = (float*) (W + 33619968);    //      1,024
    float* n_scal     = (float*) (W + 33621248);    //          4
    int*   offsets    = (int*)   (W + 33621252);    //     32,768
    int*   toklist    = (int*)   (W + 33654020);    //     65,536
    int*   idx_i32    = (int*)   (W + 33719556);    //     65,536
    int*   gcur       = (int*)   (W + 33785092);    //     32,768

    k_prep     <<<5152, 256, 0, stream>>>(x, emb, Ap, Bp, xT, esq, counts);
    k_dist     <<<2048, 512, 0, stream>>>(Ap, Bp, esq, pairs);
    k_rq       <<<256, 512, 0, stream>>>(pairs, xT, emb, esq, x, idx_i32,
                                         out + 8396802, counts, out + 1, loss_parts);
    k_ivt_stats<<<1, 256, 0, stream>>>(counts, cs, loss_parts,
                                       offsets, gcur, n_scal, out);
    k_scatter  <<<64, 256, 0, stream>>>(idx_i32, gcur, toklist);
    k_dw_final <<<NUM_EMB, 128, 0, stream>>>(xT, counts, offsets, toklist, cs, emaw,
                                             n_scal, out + 4194306, out + 6291458,
                                             out + 6299650);
}

// Round 8
// 254.442 us; speedup vs baseline: 1.1570x; 1.1121x over previous
//
#include <hip/hip_runtime.h>
#include <hip/hip_bf16.h>
#include <math.h>

#define NUM_EMB 8192
#define EMB_DIM 256
#define NTOK    16384      // 16 * 32 * 32
#define HW      1024
#define QELEMS  4194304    // 16 * 256 * 1024
#define DECAY   0.99f
#define OMD     0.01f
#define COMMIT  0.25f
#define EPS_    1e-5f
#define MARGIN  0.6f
#define NSLICE  16         // codes per slice = 512

typedef _Float16 h8 __attribute__((ext_vector_type(8)));
typedef float    f4 __attribute__((ext_vector_type(4)));

#define GLD16(gptr, lptr) \
  __builtin_amdgcn_global_load_lds((const __attribute__((address_space(1))) void*)(gptr), \
                                   (__attribute__((address_space(3))) void*)(lptr), 16, 0, 0)

__device__ __forceinline__ int imin3(int a, int b, int c) {
    int d; asm("v_min3_i32 %0, %1, %2, %3" : "=v"(d) : "v"(a), "v"(b), "v"(c)); return d;
}
__device__ __forceinline__ int imed3(int a, int b, int c) {
    int d; asm("v_med3_i32 %0, %1, %2, %3" : "=v"(d) : "v"(a), "v"(b), "v"(c)); return d;
}

// ---------------- k_prep: x->Ap(-2x, f16)+xT(f32), emb->Bp(f16), esq, zero counts --
// Ap is pre-scaled by -2 (exact pow2 f16 scale) so k_dist's MFMA accumulates -2*dot
// directly on top of a C-init of (esq+4096). Ap feeds ONLY k_dist; xT stays exact.
// Bp layout is read-order-major for k_dist: [bS][wn][t=nt*8+kc][j][lane][8] so the
// inner-loop B address is base + t*2048 elems with j folded into the load imm.
__global__ __launch_bounds__(256)
void k_prep(const float* __restrict__ x, const float* __restrict__ emb,
            _Float16* __restrict__ Ap, _Float16* __restrict__ Bp,
            float* __restrict__ xT, float* __restrict__ esq,
            float* __restrict__ counts) {
    int bb = blockIdx.x;
    if (bb < 2048) {
        int g = bb * 256 + threadIdx.x;
        int lane = g & 63;
        int kc = (g >> 6) & 7;
        int mt = g >> 9;                         // 0..1023
        int tok = mt * 16 + (lane & 15);
        int b = tok >> 10, hw = tok & 1023;
        int d0 = kc * 32 + (lane >> 4) * 8;
        const float* src = x + (size_t)b * 262144 + (size_t)d0 * 1024 + hw;
        h8 hi; float tmp[8];
        #pragma unroll
        for (int u = 0; u < 8; u++) {
            float v = src[(size_t)u * 1024];
            hi[u] = (_Float16)(v * -2.0f);
            tmp[u] = v;
        }
        *(h8*)(Ap + ((size_t)(mt * 8 + kc) * 64 + lane) * 8) = hi;
        *(float4*)(xT + (size_t)tok * 256 + d0)     = *(float4*)(&tmp[0]);
        *(float4*)(xT + (size_t)tok * 256 + d0 + 4) = *(float4*)(&tmp[4]);
    } else if (bb < 3072) {
        int g = (bb - 2048) * 256 + threadIdx.x;
        int lane = g & 63;
        int kc = (g >> 6) & 7;
        int ntp = g >> 9;                        // 0..511 global code-tile
        int n = ntp * 16 + (lane & 15);
        int d0 = kc * 32 + (lane >> 4) * 8;
        const float* src = emb + (size_t)n * EMB_DIM + d0;
        h8 hi;
        #pragma unroll
        for (int u = 0; u < 8; u++) hi[u] = (_Float16)src[u];
        // ntp = (bS<<5)|(nt<<3)|(wn<<2)|j
        int bS = ntp >> 5, nt = (ntp >> 3) & 3, wnp = (ntp >> 2) & 1, jp = ntp & 3;
        size_t off = ((size_t)bS << 17) + ((size_t)wnp << 16)
                   + (size_t)((nt * 8 + kc) * 4 + jp) * 512 + (size_t)lane * 8;
        *(h8*)(Bp + off) = hi;
    } else if (bb < 5120) {
        int k = (bb - 3072) * 4 + (threadIdx.x >> 6);
        int lane = threadIdx.x & 63;
        const float* row = emb + (size_t)k * EMB_DIM;
        float4 v = *(const float4*)(row + lane * 4);
        float s = v.x * v.x + v.y * v.y + v.z * v.z + v.w * v.w;
        #pragma unroll
        for (int m = 32; m >= 1; m >>= 1) s += __shfl_xor(s, m);
        if (lane == 0) esq[k] = s;
    } else {
        counts[(bb - 5120) * 256 + threadIdx.x] = 0.0f;
    }
}

// ---------------- k_dist: 128x512 block, 512 thr / 8 waves, r4 per-wave loop --------
// Per-wave loop: acc[2][4], 1-deep ping-pong B prefetch, bias-in-C, min3/med3 top-2.
// s_setprio(1) wraps each 8-MFMA cluster: waves drift (no loop barriers), so the CU
// scheduler can favor MFMA-entering waves over load-issuing ones (attn-like regime).
__global__ __launch_bounds__(512, 4)
void k_dist(const _Float16* __restrict__ Ap, const _Float16* __restrict__ Bp,
            const float* __restrict__ esq, float4* __restrict__ pairs) {
    __shared__ __align__(16) _Float16 Abuf[128 * 256];  // 64 KB; merge buf after loop
    float4* sv2 = (float4*)Abuf;                        // valid after post-loop barrier

    const int tid    = threadIdx.x;
    const int lane   = tid & 63;
    const int lane16 = lane & 15;
    const int w      = tid >> 6;
    const int wm     = w >> 1, wn = w & 1;  // wm 0..3: token quarter, wn 0..1: B half
    const int bS     = blockIdx.x >> 7;     // 0..15 (slice-major: L2 reuse of Bp)
    const int bM     = blockIdx.x & 127;    // 0..127 row-block of 128 tokens
    const int m0     = bM * 128;

    // stage A tile once: 64 KB contiguous from Ap
    #pragma unroll
    for (int s = 0; s < 8; s++) {
        int idx = s * 512 + tid;
        GLD16(Ap + (size_t)bM * 32768 + (size_t)idx * 8, Abuf + idx * 8);
    }

    // preload biased esq for all (nt, j) this lane will see
    float ev[16];
    #pragma unroll
    for (int nt = 0; nt < 4; nt++)
        #pragma unroll
        for (int j = 0; j < 4; j++)
            ev[nt * 4 + j] = esq[bS * 512 + nt * 128 + wn * 64 + j * 16 + lane16] + 4096.0f;

    int b1[8], s1[8];
    #pragma unroll
    for (int r = 0; r < 8; r++) { b1[r] = 0x7f7fffff; s1[r] = 0x7f7fffff; }

    __syncthreads();   // staging barrier

    const _Float16* Bptr = Bp + (size_t)bS * 131072 + (size_t)wn * 65536 + (size_t)lane * 8;
    const _Float16* Aptr = Abuf + wm * 8192 + lane * 8;

    h8 bA[4], bB[4];
    #pragma unroll
    for (int j = 0; j < 4; j++) bA[j] = *(const h8*)(Bptr + j * 512);   // t = 0

    f4 acc[2][4];

    #pragma unroll 1
    for (int mI = 0; mI < 16; mI++) {
        const int t0 = mI * 2, t1 = t0 + 1;
        const int nt = t0 >> 3;              // t0 even -> same nt for both bodies
        const int kc0 = t0 & 7, kc1 = kc0 + 1;

        // ---- body 0: consume bA, prefetch t1 into bB ----
        {
            #pragma unroll
            for (int j = 0; j < 4; j++)
                bB[j] = *(const h8*)(Bptr + (size_t)t1 * 2048 + j * 512);
            h8 aF[2];
            #pragma unroll
            for (int i = 0; i < 2; i++)
                aF[i] = *(const h8*)(Aptr + kc0 * 512 + i * 4096);
            __builtin_amdgcn_s_setprio(1);
            if (kc0 == 0) {      // chain head: C-init with biased esq
                #pragma unroll
                for (int i = 0; i < 2; i++)
                    #pragma unroll
                    for (int j = 0; j < 4; j++) {
                        const float e = ev[nt * 4 + j];
                        acc[i][j] = __builtin_amdgcn_mfma_f32_16x16x32_f16(
                                        aF[i], bA[j], (f4){e, e, e, e}, 0, 0, 0);
                    }
            } else {
                #pragma unroll
                for (int i = 0; i < 2; i++)
                    #pragma unroll
                    for (int j = 0; j < 4; j++)
                        acc[i][j] = __builtin_amdgcn_mfma_f32_16x16x32_f16(
                                        aF[i], bA[j], acc[i][j], 0, 0, 0);
            }
            __builtin_amdgcn_s_setprio(0);
        }
        // ---- body 1: consume bB, prefetch t1+1 into bA ----
        {
            if (t1 < 31) {
                #pragma unroll
                for (int j = 0; j < 4; j++)
                    bA[j] = *(const h8*)(Bptr + (size_t)(t1 + 1) * 2048 + j * 512);
            }
            h8 aF[2];
            #pragma unroll
            for (int i = 0; i < 2; i++)
                aF[i] = *(const h8*)(Aptr + kc1 * 512 + i * 4096);
            __builtin_amdgcn_s_setprio(1);
            #pragma unroll
            for (int i = 0; i < 2; i++)
                #pragma unroll
                for (int j = 0; j < 4; j++)
                    acc[i][j] = __builtin_amdgcn_mfma_f32_16x16x32_f16(
                                    aF[i], bB[j], acc[i][j], 0, 0, 0);
            __builtin_amdgcn_s_setprio(0);

            if (kc1 == 7) {      // per-nt epilogue: pack + batched top-2, no resets
                #pragma unroll
                for (int i = 0; i < 2; i++)
                    #pragma unroll
                    for (int reg = 0; reg < 4; reg++) {
                        const int r = i * 4 + reg;
                        int c0 = (__float_as_int(acc[i][0][reg]) & ~0xF) | (nt << 2) | 0;
                        int c1 = (__float_as_int(acc[i][1][reg]) & ~0xF) | (nt << 2) | 1;
                        int c2 = (__float_as_int(acc[i][2][reg]) & ~0xF) | (nt << 2) | 2;
                        int c3 = (__float_as_int(acc[i][3][reg]) & ~0xF) | (nt << 2) | 3;
                        int m1 = imed3(b1[r], c0, c1);
                        b1[r]  = imin3(b1[r], c0, c1);
                        int m2 = imed3(b1[r], c2, c3);
                        b1[r]  = imin3(b1[r], c2, c3);
                        s1[r]  = imin3(s1[r], m1, m2);
                    }
            }
        }
    }

    __syncthreads();   // all Abuf reads done -> safe to reuse LDS as sv2

    // unpack (nt,j) codes -> full indices, then cross-lane16 exact top-2 merge
    #pragma unroll
    for (int i = 0; i < 2; i++) {
        #pragma unroll
        for (int reg = 0; reg < 4; reg++) {
            const int rr = i * 4 + reg;
            int bv = b1[rr], sv = s1[rr];
            int bki = bS * 512 + ((bv >> 2) & 3) * 128 + (bv & 3) * 16 + wn * 64 + lane16;
            int ski = bS * 512 + ((sv >> 2) & 3) * 128 + (sv & 3) * 16 + wn * 64 + lane16;
            #pragma unroll
            for (int mask = 1; mask <= 8; mask <<= 1) {
                int ov  = __shfl_xor(bv, mask);  int oki  = __shfl_xor(bki, mask);
                int ov2 = __shfl_xor(sv, mask);  int oki2 = __shfl_xor(ski, mask);
                if (ov < bv || (ov == bv && oki < bki)) {
                    int ns = bv; int nsi = bki;
                    if (ov2 < ns) { ns = ov2; nsi = oki2; }
                    bv = ov; bki = oki; sv = ns; ski = nsi;
                } else if (ov < sv) { sv = ov; ski = oki; }
            }
            if (lane16 == 0) {
                int r = (wm * 2 + i) * 16 + ((lane >> 4) << 2) + reg; // row within 128
                sv2[wn * 128 + r] = make_float4(__int_as_float(bv), __int_as_float(bki),
                                                __int_as_float(sv), __int_as_float(ski));
            }
        }
    }
    __syncthreads();
    if (tid < 128) {
        float4 A = sv2[tid], C = sv2[128 + tid];
        float a1 = A.x, a2 = A.z, c1 = C.x, c2 = C.z;
        int a1i = __float_as_int(A.y), a2i = __float_as_int(A.w);
        int c1i = __float_as_int(C.y), c2i = __float_as_int(C.w);
        float b, s; int bi, si;
        if (c1 < a1 || (c1 == a1 && c1i < a1i)) {
            b = c1; bi = c1i; s = a1; si = a1i;
            if (c2 < s) { s = c2; si = c2i; }
        } else {
            b = a1; bi = a1i; s = a2; si = a2i;
            if (c1 < s) { s = c1; si = c1i; }
        }
        pairs[(size_t)(m0 + tid) * NSLICE + bS] = make_float4(b, __int_as_float(bi), s, __int_as_float(si));
    }
}

// ---------------- k_rq: fused refine (exact fp32 argmin) + coalesced q_st + loss ----
// Block = 32 consecutive tokens, 512 threads (8 waves x 4 tokens each).
// 512 blocks -> 2 blocks/CU, 16 waves/CU (was 256 blocks = 1/CU, 25% occ).
__global__ __launch_bounds__(512)
void k_rq(const float4* __restrict__ pairs, const float* __restrict__ xT,
          const float* __restrict__ emb, const float* __restrict__ esq,
          const float* __restrict__ x,
          int* __restrict__ idx_i32, float* __restrict__ out_idxf,
          float* __restrict__ counts, float* __restrict__ out_qst,
          float* __restrict__ loss_parts) {
    __shared__ float Q[32 * 257];   // winner rows, stride 257
    __shared__ float wsum[8];
    int tid = threadIdx.x;
    int lane = tid & 63, wid = tid >> 6;
    int tok0 = blockIdx.x * 32;
    int b = tok0 >> 10, hw0 = tok0 & 1023;

    for (int s = 0; s < 4; s++) {
        int tl = wid * 4 + s;
        int tok = tok0 + tl;
        float4 p = (lane < NSLICE) ? pairs[(size_t)tok * NSLICE + lane]
                                   : make_float4(3.4e38f, __int_as_float(0x7fffffff),
                                                 3.4e38f, __int_as_float(0x7fffffff));
        float v1 = p.x, v2 = p.z;
        int i1 = __float_as_int(p.y), i2 = __float_as_int(p.w);

        float bv = v1; int bi = i1;
        #pragma unroll
        for (int mask = 1; mask <= 32; mask <<= 1) {
            float ov = __shfl_xor(bv, mask); int oi = __shfl_xor(bi, mask);
            if (ov < bv || (ov == bv && oi < bi)) { bv = ov; bi = oi; }
        }
        float thresh = bv + MARGIN;
        float4 xv = *(const float4*)(xT + (size_t)tok * 256 + lane * 4);

        unsigned long long m1 = __ballot(v1 <= thresh);
        unsigned long long m2 = __ballot(v2 <= thresh);
        float bestd = 3.4e38f; int besti = 0x7fffffff;
        while (m1 | m2) {
            int k;
            if (m1) { int l = __ffsll(m1) - 1; m1 &= m1 - 1; k = __shfl(i1, l); }
            else    { int l = __ffsll(m2) - 1; m2 &= m2 - 1; k = __shfl(i2, l); }
            float4 e4 = *(const float4*)(emb + (size_t)k * EMB_DIM + lane * 4);
            float d = xv.x * e4.x + xv.y * e4.y + xv.z * e4.z + xv.w * e4.w;
            #pragma unroll
            for (int mask = 1; mask <= 32; mask <<= 1) d += __shfl_xor(d, mask);
            float dist = esq[k] - 2.0f * d;
            if (dist < bestd || (dist == bestd && k < besti)) { bestd = dist; besti = k; }
        }
        // stash winner row into LDS
        float4 e4 = *(const float4*)(emb + (size_t)besti * EMB_DIM + lane * 4);
        float* q = Q + tl * 257 + lane * 4;
        q[0] = e4.x; q[1] = e4.y; q[2] = e4.z; q[3] = e4.w;
        if (lane == 0) {
            idx_i32[tok] = besti;
            out_idxf[tok] = (float)besti;
            atomicAdd(&counts[besti], 1.0f);
        }
    }
    __syncthreads();

    // phase 2: coalesced NCHW straight-through write + loss
    int lane8 = tid & 7, dg = tid >> 3;        // dg 0..63
    int hwoff = lane8 * 4;
    float sq = 0.0f;
    #pragma unroll 2
    for (int it = 0; it < 4; it++) {
        int d = it * 64 + dg;
        const float* xb = x + (size_t)b * 262144 + (size_t)d * 1024 + hw0 + hwoff;
        float4 xv = *(const float4*)xb;
        float q0 = Q[(hwoff + 0) * 257 + d];
        float q1 = Q[(hwoff + 1) * 257 + d];
        float q2 = Q[(hwoff + 2) * 257 + d];
        float q3 = Q[(hwoff + 3) * 257 + d];
        float d0 = q0 - xv.x, d1 = q1 - xv.y, d2 = q2 - xv.z, d3 = q3 - xv.w;
        float4 o; o.x = xv.x + d0; o.y = xv.y + d1; o.z = xv.z + d2; o.w = xv.w + d3;
        *(float4*)(out_qst + (size_t)b * 262144 + (size_t)d * 1024 + hw0 + hwoff) = o;
        sq += d0 * d0 + d1 * d1 + d2 * d2 + d3 * d3;
    }
    #pragma unroll
    for (int m = 32; m >= 1; m >>= 1) sq += __shfl_xor(sq, m);
    if (lane == 0) wsum[wid] = sq;
    __syncthreads();
    if (tid == 0) {
        float t = 0.0f;
        #pragma unroll
        for (int u = 0; u < 8; u++) t += wsum[u];
        loss_parts[blockIdx.x] = t;
    }
}

// ---------------- k_ivt_stats: prefix sum -> offsets/gcur + n/perplexity/loss -------
__global__ __launch_bounds__(256)
void k_ivt_stats(const float* __restrict__ counts,
                 const float* __restrict__ cs, const float* __restrict__ loss_parts,
                 int* __restrict__ offsets, int* __restrict__ gcur,
                 float* __restrict__ n_out, float* __restrict__ out) {
    __shared__ int part[256];
    int t = threadIdx.x;
    int base = t * 32;
    int loc[32]; int s = 0;
    #pragma unroll
    for (int u = 0; u < 32; u++) { loc[u] = s; s += (int)counts[base + u]; }
    part[t] = s;
    __syncthreads();
    for (int off = 1; off < 256; off <<= 1) {
        int add = (t >= off) ? part[t - off] : 0;
        __syncthreads();
        part[t] += add;
        __syncthreads();
    }
    int excl = part[t] - s;
    #pragma unroll
    for (int u = 0; u < 32; u++) {
        int o = excl + loc[u];
        offsets[base + u] = o;
        gcur[base + u] = o;
    }

    float s1 = 0.0f, s2 = 0.0f;
    for (int k = t; k < NUM_EMB; k += 256) {
        float c = counts[k];
        s1 += cs[k] * DECAY + OMD * c;
        float pb = c / (float)NTOK;
        s2 += pb * logf(pb + 1e-10f);
    }
    float s3 = loss_parts[t] + loss_parts[t + 256];   // 512 k_rq blocks
    #pragma unroll
    for (int m = 32; m >= 1; m >>= 1) {
        s1 += __shfl_xor(s1, m);
        s2 += __shfl_xor(s2, m);
        s3 += __shfl_xor(s3, m);
    }
    __shared__ float w1[4], w2[4], w3[4];
    int lane = t & 63, wid = t >> 6;
    if (lane == 0) { w1[wid] = s1; w2[wid] = s2; w3[wid] = s3; }
    __syncthreads();
    if (t == 0) {
        float n  = w1[0] + w1[1] + w1[2] + w1[3];
        float e2 = w2[0] + w2[1] + w2[2] + w2[3];
        float ls = w3[0] + w3[1] + w3[2] + w3[3];
        n_out[0] = n;
        out[4194305] = expf(-e2);                 // perplexity
        out[0] = COMMIT * ls / (float)QELEMS;     // loss
    }
}

// ---------------- k_scatter: parallel toklist build (device-scope atomics) ----------
// List order within a code differs from any serial order; consumers only sum -> OK.
__global__ __launch_bounds__(256)
void k_scatter(const int* __restrict__ idx_i32, int* __restrict__ gcur,
               int* __restrict__ toklist) {
    int n = blockIdx.x * 256 + threadIdx.x;
    int k = idx_i32[n];
    int p = atomicAdd(&gcur[k], 1);
    toklist[p] = n;
}

// ---------------- k_dw_final: 4-wave per-code dw row-sum + EMA outputs --------------
__global__ __launch_bounds__(256)
void k_dw_final(const float* __restrict__ xT, const float* __restrict__ counts,
                const int* __restrict__ offsets, const int* __restrict__ toklist,
                const float* __restrict__ cs, const float* __restrict__ emaw,
                const float* __restrict__ n_in,
                float* __restrict__ out_emb, float* __restrict__ out_cs,
                float* __restrict__ out_emaw) {
    __shared__ float4 sbuf[4][64];
    int k = blockIdx.x;
    int lane = threadIdx.x & 63, wid = threadIdx.x >> 6;
    int c = (int)counts[k];
    int off = offsets[k];
    float a0 = 0, a1 = 0, a2 = 0, a3 = 0;
    for (int t = wid; t < c; t += 4) {
        int tok = toklist[off + t];
        float4 v = *(const float4*)(xT + (size_t)tok * 256 + lane * 4);
        a0 += v.x; a1 += v.y; a2 += v.z; a3 += v.w;
    }
    sbuf[wid][lane] = make_float4(a0, a1, a2, a3);
    __syncthreads();
    if (wid == 0) {
        float4 p0 = sbuf[0][lane], p1 = sbuf[1][lane];
        float4 p2 = sbuf[2][lane], p3 = sbuf[3][lane];
        a0 = p0.x + p1.x + p2.x + p3.x;
        a1 = p0.y + p1.y + p2.y + p3.y;
        a2 = p0.z + p1.z + p2.z + p3.z;
        a3 = p0.w + p1.w + p2.w + p3.w;
        float n = n_in[0];
        float pre  = cs[k] * DECAY + OMD * counts[k];
        float cssm = (pre + EPS_) / (n + (float)NUM_EMB * EPS_) * n;
        size_t o = (size_t)k * EMB_DIM + lane * 4;
        float4 ew = *(const float4*)(emaw + o);
        float4 wv;
        wv.x = ew.x * DECAY + OMD * a0;
        wv.y = ew.y * DECAY + OMD * a1;
        wv.z = ew.z * DECAY + OMD * a2;
        wv.w = ew.w * DECAY + OMD * a3;
        *(float4*)(out_emaw + o) = wv;
        float4 obv; obv.x = wv.x / cssm; obv.y = wv.y / cssm;
        obv.z = wv.z / cssm; obv.w = wv.w / cssm;
        *(float4*)(out_emb + o) = obv;
        if (lane == 0) out_cs[k] = cssm;
    }
}

extern "C" void kernel_launch(void* const* d_in, const int* in_sizes, int n_in,
                              void* d_out, int out_size, void* d_ws, size_t ws_size,
                              hipStream_t stream) {
    const float* x    = (const float*)d_in[0];   // [16,256,32,32]
    const float* emb  = (const float*)d_in[1];   // [8192,256]
    const float* cs   = (const float*)d_in[2];   // [8192]
    const float* emaw = (const float*)d_in[3];   // [8192,256]
    float* out = (float*)d_out;

    // workspace layout (bytes)
    char* W = (char*)d_ws;
    _Float16* Ap      = (_Float16*)(W);             //  8,388,608
    _Float16* Bp      = (_Float16*)(W + 8388608);   //  4,194,304
    float*  xT        = (float*) (W + 12582912);    // 16,777,216
    float4* pairs     = (float4*)(W + 29360128);    //  4,194,304
    float* esq        = (float*) (W + 33554432);    //     32,768
    float* counts     = (float*) (W + 33587200);    //     32,768
    float* n_scal     = (float*) (W + 33621248);    //          4
    int*   offsets    = (int*)   (W + 33621252);    //     32,768
    int*   toklist    = (int*)   (W + 33654020);    //     65,536
    int*   idx_i32    = (int*)   (W + 33719556);    //     65,536
    int*   gcur       = (int*)   (W + 33785092);    //     32,768
    float* loss_parts = (float*) (W + 33817860);    //      2,048 (512 entries)

    k_prep     <<<5152, 256, 0, stream>>>(x, emb, Ap, Bp, xT, esq, counts);
    k_dist     <<<2048, 512, 0, stream>>>(Ap, Bp, esq, pairs);
    k_rq       <<<512, 512, 0, stream>>>(pairs, xT, emb, esq, x, idx_i32,
                                         out + 8396802, counts, out + 1, loss_parts);
    k_ivt_stats<<<1, 256, 0, stream>>>(counts, cs, loss_parts,
                                       offsets, gcur, n_scal, out);
    k_scatter  <<<64, 256, 0, stream>>>(idx_i32, gcur, toklist);
    k_dw_final <<<NUM_EMB, 256, 0, stream>>>(xT, counts, offsets, toklist, cs, emaw,
                                             n_scal, out + 4194306, out + 6291458,
                                             out + 6299650);
}

// Round 9
// 251.287 us; speedup vs baseline: 1.1716x; 1.0126x over previous
//
#include <hip/hip_runtime.h>
#include <hip/hip_bf16.h>
#include <math.h>

#define NUM_EMB 8192
#define EMB_DIM 256
#define NTOK    16384      // 16 * 32 * 32
#define HW      1024
#define QELEMS  4194304    // 16 * 256 * 1024
#define DECAY   0.99f
#define OMD     0.01f
#define COMMIT  0.25f
#define EPS_    1e-5f
#define MARGIN  0.6f
#define NSLICE  16         // codes per slice = 512

typedef _Float16 h8 __attribute__((ext_vector_type(8)));
typedef float    f4 __attribute__((ext_vector_type(4)));

#define GLD16(gptr, lptr) \
  __builtin_amdgcn_global_load_lds((const __attribute__((address_space(1))) void*)(gptr), \
                                   (__attribute__((address_space(3))) void*)(lptr), 16, 0, 0)

__device__ __forceinline__ int imin3(int a, int b, int c) {
    int d; asm("v_min3_i32 %0, %1, %2, %3" : "=v"(d) : "v"(a), "v"(b), "v"(c)); return d;
}
__device__ __forceinline__ int imed3(int a, int b, int c) {
    int d; asm("v_med3_i32 %0, %1, %2, %3" : "=v"(d) : "v"(a), "v"(b), "v"(c)); return d;
}

// ---------------- k_prep: x->Ap(-2x, f16)+xT(f32), emb->Bp(f16), esq, zero counts --
// Ap is pre-scaled by -2 (exact pow2 f16 scale) so k_dist's MFMA accumulates -2*dot
// directly on top of a C-init of (esq+4096). Ap feeds ONLY k_dist; xT stays exact.
// Bp layout is read-order-major for k_dist: [bS][wn][t=nt*8+kc][j][lane][8] so the
// inner-loop B address is base + t*2048 elems with j folded into the load imm.
__global__ __launch_bounds__(256)
void k_prep(const float* __restrict__ x, const float* __restrict__ emb,
            _Float16* __restrict__ Ap, _Float16* __restrict__ Bp,
            float* __restrict__ xT, float* __restrict__ esq,
            float* __restrict__ counts) {
    int bb = blockIdx.x;
    if (bb < 2048) {
        int g = bb * 256 + threadIdx.x;
        int lane = g & 63;
        int kc = (g >> 6) & 7;
        int mt = g >> 9;                         // 0..1023
        int tok = mt * 16 + (lane & 15);
        int b = tok >> 10, hw = tok & 1023;
        int d0 = kc * 32 + (lane >> 4) * 8;
        const float* src = x + (size_t)b * 262144 + (size_t)d0 * 1024 + hw;
        h8 hi; float tmp[8];
        #pragma unroll
        for (int u = 0; u < 8; u++) {
            float v = src[(size_t)u * 1024];
            hi[u] = (_Float16)(v * -2.0f);
            tmp[u] = v;
        }
        *(h8*)(Ap + ((size_t)(mt * 8 + kc) * 64 + lane) * 8) = hi;
        *(float4*)(xT + (size_t)tok * 256 + d0)     = *(float4*)(&tmp[0]);
        *(float4*)(xT + (size_t)tok * 256 + d0 + 4) = *(float4*)(&tmp[4]);
    } else if (bb < 3072) {
        int g = (bb - 2048) * 256 + threadIdx.x;
        int lane = g & 63;
        int kc = (g >> 6) & 7;
        int ntp = g >> 9;                        // 0..511 global code-tile
        int n = ntp * 16 + (lane & 15);
        int d0 = kc * 32 + (lane >> 4) * 8;
        const float* src = emb + (size_t)n * EMB_DIM + d0;
        h8 hi;
        #pragma unroll
        for (int u = 0; u < 8; u++) hi[u] = (_Float16)src[u];
        // ntp = (bS<<5)|(nt<<3)|(wn<<2)|j
        int bS = ntp >> 5, nt = (ntp >> 3) & 3, wnp = (ntp >> 2) & 1, jp = ntp & 3;
        size_t off = ((size_t)bS << 17) + ((size_t)wnp << 16)
                   + (size_t)((nt * 8 + kc) * 4 + jp) * 512 + (size_t)lane * 8;
        *(h8*)(Bp + off) = hi;
    } else if (bb < 5120) {
        int k = (bb - 3072) * 4 + (threadIdx.x >> 6);
        int lane = threadIdx.x & 63;
        const float* row = emb + (size_t)k * EMB_DIM;
        float4 v = *(const float4*)(row + lane * 4);
        float s = v.x * v.x + v.y * v.y + v.z * v.z + v.w * v.w;
        #pragma unroll
        for (int m = 32; m >= 1; m >>= 1) s += __shfl_xor(s, m);
        if (lane == 0) esq[k] = s;
    } else {
        counts[(bb - 5120) * 256 + threadIdx.x] = 0.0f;
    }
}

// ---------------- k_dist: 128x512 block, 512 thr / 8 waves, r4 per-wave loop --------
// Per-wave loop: acc[2][4], 1-deep ping-pong B prefetch, bias-in-C, min3/med3 top-2.
// NOTE: s_setprio was tried (r8) and REGRESSED 15% — symmetric waves, no role split.
__global__ __launch_bounds__(512, 4)
void k_dist(const _Float16* __restrict__ Ap, const _Float16* __restrict__ Bp,
            const float* __restrict__ esq, float4* __restrict__ pairs) {
    __shared__ __align__(16) _Float16 Abuf[128 * 256];  // 64 KB; merge buf after loop
    float4* sv2 = (float4*)Abuf;                        // valid after post-loop barrier

    const int tid    = threadIdx.x;
    const int lane   = tid & 63;
    const int lane16 = lane & 15;
    const int w      = tid >> 6;
    const int wm     = w >> 1, wn = w & 1;  // wm 0..3: token quarter, wn 0..1: B half
    const int bS     = blockIdx.x >> 7;     // 0..15 (slice-major: L2 reuse of Bp)
    const int bM     = blockIdx.x & 127;    // 0..127 row-block of 128 tokens
    const int m0     = bM * 128;

    // stage A tile once: 64 KB contiguous from Ap
    #pragma unroll
    for (int s = 0; s < 8; s++) {
        int idx = s * 512 + tid;
        GLD16(Ap + (size_t)bM * 32768 + (size_t)idx * 8, Abuf + idx * 8);
    }

    // preload biased esq for all (nt, j) this lane will see
    float ev[16];
    #pragma unroll
    for (int nt = 0; nt < 4; nt++)
        #pragma unroll
        for (int j = 0; j < 4; j++)
            ev[nt * 4 + j] = esq[bS * 512 + nt * 128 + wn * 64 + j * 16 + lane16] + 4096.0f;

    int b1[8], s1[8];
    #pragma unroll
    for (int r = 0; r < 8; r++) { b1[r] = 0x7f7fffff; s1[r] = 0x7f7fffff; }

    __syncthreads();   // staging barrier

    const _Float16* Bptr = Bp + (size_t)bS * 131072 + (size_t)wn * 65536 + (size_t)lane * 8;
    const _Float16* Aptr = Abuf + wm * 8192 + lane * 8;

    h8 bA[4], bB[4];
    #pragma unroll
    for (int j = 0; j < 4; j++) bA[j] = *(const h8*)(Bptr + j * 512);   // t = 0

    f4 acc[2][4];

    #pragma unroll 1
    for (int mI = 0; mI < 16; mI++) {
        const int t0 = mI * 2, t1 = t0 + 1;
        const int nt = t0 >> 3;              // t0 even -> same nt for both bodies
        const int kc0 = t0 & 7, kc1 = kc0 + 1;

        // ---- body 0: consume bA, prefetch t1 into bB ----
        {
            #pragma unroll
            for (int j = 0; j < 4; j++)
                bB[j] = *(const h8*)(Bptr + (size_t)t1 * 2048 + j * 512);
            h8 aF[2];
            #pragma unroll
            for (int i = 0; i < 2; i++)
                aF[i] = *(const h8*)(Aptr + kc0 * 512 + i * 4096);
            if (kc0 == 0) {      // chain head: C-init with biased esq
                #pragma unroll
                for (int i = 0; i < 2; i++)
                    #pragma unroll
                    for (int j = 0; j < 4; j++) {
                        const float e = ev[nt * 4 + j];
                        acc[i][j] = __builtin_amdgcn_mfma_f32_16x16x32_f16(
                                        aF[i], bA[j], (f4){e, e, e, e}, 0, 0, 0);
                    }
            } else {
                #pragma unroll
                for (int i = 0; i < 2; i++)
                    #pragma unroll
                    for (int j = 0; j < 4; j++)
                        acc[i][j] = __builtin_amdgcn_mfma_f32_16x16x32_f16(
                                        aF[i], bA[j], acc[i][j], 0, 0, 0);
            }
        }
        // ---- body 1: consume bB, prefetch t1+1 into bA ----
        {
            if (t1 < 31) {
                #pragma unroll
                for (int j = 0; j < 4; j++)
                    bA[j] = *(const h8*)(Bptr + (size_t)(t1 + 1) * 2048 + j * 512);
            }
            h8 aF[2];
            #pragma unroll
            for (int i = 0; i < 2; i++)
                aF[i] = *(const h8*)(Aptr + kc1 * 512 + i * 4096);
            #pragma unroll
            for (int i = 0; i < 2; i++)
                #pragma unroll
                for (int j = 0; j < 4; j++)
                    acc[i][j] = __builtin_amdgcn_mfma_f32_16x16x32_f16(
                                    aF[i], bB[j], acc[i][j], 0, 0, 0);

            if (kc1 == 7) {      // per-nt epilogue: pack + batched top-2, no resets
                #pragma unroll
                for (int i = 0; i < 2; i++)
                    #pragma unroll
                    for (int reg = 0; reg < 4; reg++) {
                        const int r = i * 4 + reg;
                        int c0 = (__float_as_int(acc[i][0][reg]) & ~0xF) | (nt << 2) | 0;
                        int c1 = (__float_as_int(acc[i][1][reg]) & ~0xF) | (nt << 2) | 1;
                        int c2 = (__float_as_int(acc[i][2][reg]) & ~0xF) | (nt << 2) | 2;
                        int c3 = (__float_as_int(acc[i][3][reg]) & ~0xF) | (nt << 2) | 3;
                        int m1 = imed3(b1[r], c0, c1);
                        b1[r]  = imin3(b1[r], c0, c1);
                        int m2 = imed3(b1[r], c2, c3);
                        b1[r]  = imin3(b1[r], c2, c3);
                        s1[r]  = imin3(s1[r], m1, m2);
                    }
            }
        }
    }

    __syncthreads();   // all Abuf reads done -> safe to reuse LDS as sv2

    // unpack (nt,j) codes -> full indices, then cross-lane16 exact top-2 merge
    #pragma unroll
    for (int i = 0; i < 2; i++) {
        #pragma unroll
        for (int reg = 0; reg < 4; reg++) {
            const int rr = i * 4 + reg;
            int bv = b1[rr], sv = s1[rr];
            int bki = bS * 512 + ((bv >> 2) & 3) * 128 + (bv & 3) * 16 + wn * 64 + lane16;
            int ski = bS * 512 + ((sv >> 2) & 3) * 128 + (sv & 3) * 16 + wn * 64 + lane16;
            #pragma unroll
            for (int mask = 1; mask <= 8; mask <<= 1) {
                int ov  = __shfl_xor(bv, mask);  int oki  = __shfl_xor(bki, mask);
                int ov2 = __shfl_xor(sv, mask);  int oki2 = __shfl_xor(ski, mask);
                if (ov < bv || (ov == bv && oki < bki)) {
                    int ns = bv; int nsi = bki;
                    if (ov2 < ns) { ns = ov2; nsi = oki2; }
                    bv = ov; bki = oki; sv = ns; ski = nsi;
                } else if (ov < sv) { sv = ov; ski = oki; }
            }
            if (lane16 == 0) {
                int r = (wm * 2 + i) * 16 + ((lane >> 4) << 2) + reg; // row within 128
                sv2[wn * 128 + r] = make_float4(__int_as_float(bv), __int_as_float(bki),
                                                __int_as_float(sv), __int_as_float(ski));
            }
        }
    }
    __syncthreads();
    if (tid < 128) {
        float4 A = sv2[tid], C = sv2[128 + tid];
        float a1 = A.x, a2 = A.z, c1 = C.x, c2 = C.z;
        int a1i = __float_as_int(A.y), a2i = __float_as_int(A.w);
        int c1i = __float_as_int(C.y), c2i = __float_as_int(C.w);
        float b, s; int bi, si;
        if (c1 < a1 || (c1 == a1 && c1i < a1i)) {
            b = c1; bi = c1i; s = a1; si = a1i;
            if (c2 < s) { s = c2; si = c2i; }
        } else {
            b = a1; bi = a1i; s = a2; si = a2i;
            if (c1 < s) { s = c1; si = c1i; }
        }
        pairs[(size_t)(m0 + tid) * NSLICE + bS] = make_float4(b, __int_as_float(bi), s, __int_as_float(si));
    }
}

// ---------------- k_rq: fused refine (exact fp32 argmin) + coalesced q_st + loss ----
// Block = 16 consecutive tokens, 512 threads (8 waves x 2 tokens each).
// 1024 blocks -> 4 blocks/CU, 32 waves/CU; serial refine depth halved vs r8.
__global__ __launch_bounds__(512)
void k_rq(const float4* __restrict__ pairs, const float* __restrict__ xT,
          const float* __restrict__ emb, const float* __restrict__ esq,
          const float* __restrict__ x,
          int* __restrict__ idx_i32, float* __restrict__ out_idxf,
          float* __restrict__ counts, float* __restrict__ out_qst,
          float* __restrict__ loss_parts) {
    __shared__ float Q[16 * 257];   // winner rows, stride 257
    __shared__ float wsum[8];
    int tid = threadIdx.x;
    int lane = tid & 63, wid = tid >> 6;
    int tok0 = blockIdx.x * 16;
    int b = tok0 >> 10, hw0 = tok0 & 1023;

    for (int s = 0; s < 2; s++) {
        int tl = wid * 2 + s;
        int tok = tok0 + tl;
        float4 p = (lane < NSLICE) ? pairs[(size_t)tok * NSLICE + lane]
                                   : make_float4(3.4e38f, __int_as_float(0x7fffffff),
                                                 3.4e38f, __int_as_float(0x7fffffff));
        float v1 = p.x, v2 = p.z;
        int i1 = __float_as_int(p.y), i2 = __float_as_int(p.w);

        float bv = v1; int bi = i1;
        #pragma unroll
        for (int mask = 1; mask <= 32; mask <<= 1) {
            float ov = __shfl_xor(bv, mask); int oi = __shfl_xor(bi, mask);
            if (ov < bv || (ov == bv && oi < bi)) { bv = ov; bi = oi; }
        }
        float thresh = bv + MARGIN;
        float4 xv = *(const float4*)(xT + (size_t)tok * 256 + lane * 4);

        unsigned long long m1 = __ballot(v1 <= thresh);
        unsigned long long m2 = __ballot(v2 <= thresh);
        float bestd = 3.4e38f; int besti = 0x7fffffff;
        while (m1 | m2) {
            int k;
            if (m1) { int l = __ffsll(m1) - 1; m1 &= m1 - 1; k = __shfl(i1, l); }
            else    { int l = __ffsll(m2) - 1; m2 &= m2 - 1; k = __shfl(i2, l); }
            float4 e4 = *(const float4*)(emb + (size_t)k * EMB_DIM + lane * 4);
            float d = xv.x * e4.x + xv.y * e4.y + xv.z * e4.z + xv.w * e4.w;
            #pragma unroll
            for (int mask = 1; mask <= 32; mask <<= 1) d += __shfl_xor(d, mask);
            float dist = esq[k] - 2.0f * d;
            if (dist < bestd || (dist == bestd && k < besti)) { bestd = dist; besti = k; }
        }
        // stash winner row into LDS
        float4 e4 = *(const float4*)(emb + (size_t)besti * EMB_DIM + lane * 4);
        float* q = Q + tl * 257 + lane * 4;
        q[0] = e4.x; q[1] = e4.y; q[2] = e4.z; q[3] = e4.w;
        if (lane == 0) {
            idx_i32[tok] = besti;
            out_idxf[tok] = (float)besti;
            atomicAdd(&counts[besti], 1.0f);
        }
    }
    __syncthreads();

    // phase 2: coalesced NCHW straight-through write + loss
    int lane4 = tid & 3, dg = tid >> 2;        // dg 0..127
    int hwoff = lane4 * 4;
    float sq = 0.0f;
    #pragma unroll 2
    for (int it = 0; it < 2; it++) {
        int d = it * 128 + dg;
        const float* xb = x + (size_t)b * 262144 + (size_t)d * 1024 + hw0 + hwoff;
        float4 xv = *(const float4*)xb;
        float q0 = Q[(hwoff + 0) * 257 + d];
        float q1 = Q[(hwoff + 1) * 257 + d];
        float q2 = Q[(hwoff + 2) * 257 + d];
        float q3 = Q[(hwoff + 3) * 257 + d];
        float d0 = q0 - xv.x, d1 = q1 - xv.y, d2 = q2 - xv.z, d3 = q3 - xv.w;
        float4 o; o.x = xv.x + d0; o.y = xv.y + d1; o.z = xv.z + d2; o.w = xv.w + d3;
        *(float4*)(out_qst + (size_t)b * 262144 + (size_t)d * 1024 + hw0 + hwoff) = o;
        sq += d0 * d0 + d1 * d1 + d2 * d2 + d3 * d3;
    }
    #pragma unroll
    for (int m = 32; m >= 1; m >>= 1) sq += __shfl_xor(sq, m);
    if (lane == 0) wsum[wid] = sq;
    __syncthreads();
    if (tid == 0) {
        float t = 0.0f;
        #pragma unroll
        for (int u = 0; u < 8; u++) t += wsum[u];
        loss_parts[blockIdx.x] = t;
    }
}

// ---------------- k_ivt_stats: prefix sum -> offsets/gcur + n/perplexity/loss -------
__global__ __launch_bounds__(256)
void k_ivt_stats(const float* __restrict__ counts,
                 const float* __restrict__ cs, const float* __restrict__ loss_parts,
                 int* __restrict__ offsets, int* __restrict__ gcur,
                 float* __restrict__ n_out, float* __restrict__ out) {
    __shared__ int part[256];
    int t = threadIdx.x;
    int base = t * 32;
    int loc[32]; int s = 0;
    #pragma unroll
    for (int u = 0; u < 32; u++) { loc[u] = s; s += (int)counts[base + u]; }
    part[t] = s;
    __syncthreads();
    for (int off = 1; off < 256; off <<= 1) {
        int add = (t >= off) ? part[t - off] : 0;
        __syncthreads();
        part[t] += add;
        __syncthreads();
    }
    int excl = part[t] - s;
    #pragma unroll
    for (int u = 0; u < 32; u++) {
        int o = excl + loc[u];
        offsets[base + u] = o;
        gcur[base + u] = o;
    }

    float s1 = 0.0f, s2 = 0.0f;
    for (int k = t; k < NUM_EMB; k += 256) {
        float c = counts[k];
        s1 += cs[k] * DECAY + OMD * c;
        float pb = c / (float)NTOK;
        s2 += pb * logf(pb + 1e-10f);
    }
    float s3 = loss_parts[t] + loss_parts[t + 256]
             + loss_parts[t + 512] + loss_parts[t + 768];   // 1024 k_rq blocks
    #pragma unroll
    for (int m = 32; m >= 1; m >>= 1) {
        s1 += __shfl_xor(s1, m);
        s2 += __shfl_xor(s2, m);
        s3 += __shfl_xor(s3, m);
    }
    __shared__ float w1[4], w2[4], w3[4];
    int lane = t & 63, wid = t >> 6;
    if (lane == 0) { w1[wid] = s1; w2[wid] = s2; w3[wid] = s3; }
    __syncthreads();
    if (t == 0) {
        float n  = w1[0] + w1[1] + w1[2] + w1[3];
        float e2 = w2[0] + w2[1] + w2[2] + w2[3];
        float ls = w3[0] + w3[1] + w3[2] + w3[3];
        n_out[0] = n;
        out[4194305] = expf(-e2);                 // perplexity
        out[0] = COMMIT * ls / (float)QELEMS;     // loss
    }
}

// ---------------- k_scatter: parallel toklist build (device-scope atomics) ----------
// List order within a code differs from any serial order; consumers only sum -> OK.
__global__ __launch_bounds__(128)
void k_scatter(const int* __restrict__ idx_i32, int* __restrict__ gcur,
               int* __restrict__ toklist) {
    int n = blockIdx.x * 128 + threadIdx.x;
    int k = idx_i32[n];
    int p = atomicAdd(&gcur[k], 1);
    toklist[p] = n;
}

// ---------------- k_dw_final: 4-wave per-code dw row-sum + EMA outputs --------------
__global__ __launch_bounds__(256)
void k_dw_final(const float* __restrict__ xT, const float* __restrict__ counts,
                const int* __restrict__ offsets, const int* __restrict__ toklist,
                const float* __restrict__ cs, const float* __restrict__ emaw,
                const float* __restrict__ n_in,
                float* __restrict__ out_emb, float* __restrict__ out_cs,
                float* __restrict__ out_emaw) {
    __shared__ float4 sbuf[4][64];
    int k = blockIdx.x;
    int lane = threadIdx.x & 63, wid = threadIdx.x >> 6;
    int c = (int)counts[k];
    int off = offsets[k];
    float a0 = 0, a1 = 0, a2 = 0, a3 = 0;
    for (int t = wid; t < c; t += 4) {
        int tok = toklist[off + t];
        float4 v = *(const float4*)(xT + (size_t)tok * 256 + lane * 4);
        a0 += v.x; a1 += v.y; a2 += v.z; a3 += v.w;
    }
    sbuf[wid][lane] = make_float4(a0, a1, a2, a3);
    __syncthreads();
    if (wid == 0) {
        float4 p0 = sbuf[0][lane], p1 = sbuf[1][lane];
        float4 p2 = sbuf[2][lane], p3 = sbuf[3][lane];
        a0 = p0.x + p1.x + p2.x + p3.x;
        a1 = p0.y + p1.y + p2.y + p3.y;
        a2 = p0.z + p1.z + p2.z + p3.z;
        a3 = p0.w + p1.w + p2.w + p3.w;
        float n = n_in[0];
        float pre  = cs[k] * DECAY + OMD * counts[k];
        float cssm = (pre + EPS_) / (n + (float)NUM_EMB * EPS_) * n;
        size_t o = (size_t)k * EMB_DIM + lane * 4;
        float4 ew = *(const float4*)(emaw + o);
        float4 wv;
        wv.x = ew.x * DECAY + OMD * a0;
        wv.y = ew.y * DECAY + OMD * a1;
        wv.z = ew.z * DECAY + OMD * a2;
        wv.w = ew.w * DECAY + OMD * a3;
        *(float4*)(out_emaw + o) = wv;
        float4 obv; obv.x = wv.x / cssm; obv.y = wv.y / cssm;
        obv.z = wv.z / cssm; obv.w = wv.w / cssm;
        *(float4*)(out_emb + o) = obv;
        if (lane == 0) out_cs[k] = cssm;
    }
}

extern "C" void kernel_launch(void* const* d_in, const int* in_sizes, int n_in,
                              void* d_out, int out_size, void* d_ws, size_t ws_size,
                              hipStream_t stream) {
    const float* x    = (const float*)d_in[0];   // [16,256,32,32]
    const float* emb  = (const float*)d_in[1];   // [8192,256]
    const float* cs   = (const float*)d_in[2];   // [8192]
    const float* emaw = (const float*)d_in[3];   // [8192,256]
    float* out = (float*)d_out;

    // workspace layout (bytes)
    char* W = (char*)d_ws;
    _Float16* Ap      = (_Float16*)(W);             //  8,388,608
    _Float16* Bp      = (_Float16*)(W + 8388608);   //  4,194,304
    float*  xT        = (float*) (W + 12582912);    // 16,777,216
    float4* pairs     = (float4*)(W + 29360128);    //  4,194,304
    float* esq        = (float*) (W + 33554432);    //     32,768
    float* counts     = (float*) (W + 33587200);    //     32,768
    float* n_scal     = (float*) (W + 33621248);    //          4
    int*   offsets    = (int*)   (W + 33621252);    //     32,768
    int*   toklist    = (int*)   (W + 33654020);    //     65,536
    int*   idx_i32    = (int*)   (W + 33719556);    //     65,536
    int*   gcur       = (int*)   (W + 33785092);    //     32,768
    float* loss_parts = (float*) (W + 33817860);    //      4,096 (1024 entries)

    k_prep     <<<5152, 256, 0, stream>>>(x, emb, Ap, Bp, xT, esq, counts);
    k_dist     <<<2048, 512, 0, stream>>>(Ap, Bp, esq, pairs);
    k_rq       <<<1024, 512, 0, stream>>>(pairs, xT, emb, esq, x, idx_i32,
                                          out + 8396802, counts, out + 1, loss_parts);
    k_ivt_stats<<<1, 256, 0, stream>>>(counts, cs, loss_parts,
                                       offsets, gcur, n_scal, out);
    k_scatter  <<<128, 128, 0, stream>>>(idx_i32, gcur, toklist);
    k_dw_final <<<NUM_EMB, 256, 0, stream>>>(xT, counts, offsets, toklist, cs, emaw,
                                             n_scal, out + 4194306, out + 6291458,
                                             out + 6299650);
}